// Round 1
// baseline (421.085 us; speedup 1.0000x reference)
//
#include <hip/hip_runtime.h>
#include <stdint.h>

typedef _Float16 f16;
typedef _Float16 f16x8 __attribute__((ext_vector_type(8)));
typedef _Float16 f16x4 __attribute__((ext_vector_type(4)));
typedef _Float16 f16x2 __attribute__((ext_vector_type(2)));
typedef float f32x4 __attribute__((ext_vector_type(4)));

#define AS1 __attribute__((address_space(1)))
#define AS3 __attribute__((address_space(3)))

__device__ __forceinline__ void gl_lds16(const void* g, void* l) {
  __builtin_amdgcn_global_load_lds((const AS1 uint32_t*)g, (AS3 uint32_t*)l, 16, 0, 0);
}

// ---------------- prep: x (f32) -> xh (f16) ----------------
__global__ void k_prep_x(const float* __restrict__ x, f16* __restrict__ xh) {
  int i = (blockIdx.x * 256 + threadIdx.x) * 4;
  float4 v = *(const float4*)(x + i);
  f16x4 o = { (f16)v.x, (f16)v.y, (f16)v.z, (f16)v.w };
  *(f16x4*)(xh + i) = o;
}

// ---------------- prep: W (K x N, f32) -> Wt (N x K, f16) ----------------
__global__ void k_prep_wt(const float* __restrict__ Wq, const float* __restrict__ Wk,
                          const float* __restrict__ Wv, const float* __restrict__ Wo,
                          f16* __restrict__ Wqt, f16* __restrict__ Wkt,
                          f16* __restrict__ Wvt, f16* __restrict__ Wot) {
  __shared__ __align__(16) f16 lt[64][72];   // +8 pad keeps 16B row alignment
  const float* src; f16* dst;
  switch (blockIdx.z) {
    case 0: src = Wq; dst = Wqt; break;
    case 1: src = Wk; dst = Wkt; break;
    case 2: src = Wv; dst = Wvt; break;
    default: src = Wo; dst = Wot; break;
  }
  int n0 = blockIdx.x * 64, k0 = blockIdx.y * 64;
  int t = threadIdx.x;
  int kk = t >> 4;         // 0..15
  int nn = (t & 15) * 4;   // 0..60
  #pragma unroll
  for (int p = 0; p < 4; ++p) {
    int k = kk + p * 16;
    float4 v = *(const float4*)(src + (size_t)(k0 + k) * 1024 + n0 + nn);
    lt[nn + 0][k] = (f16)v.x;
    lt[nn + 1][k] = (f16)v.y;
    lt[nn + 2][k] = (f16)v.z;
    lt[nn + 3][k] = (f16)v.w;
  }
  __syncthreads();
  int row = t >> 2;          // 0..63
  int kp = (t & 3) * 16;
  f16* d = dst + (size_t)(n0 + row) * 1024 + k0 + kp;
  *(f16x8*)d       = *(const f16x8*)&lt[row][kp];
  *(f16x8*)(d + 8) = *(const f16x8*)&lt[row][kp + 8];
}

// ---------------- GEMM: C(MxN) = A(MxK=1024) * Bt^T, fp16 in / fp32 acc ----
// MODE 0: A=xh(4096xK), Bt0=Wqt, Bt1=Wkt; out Q16,K16 as (b,h,t,d) f16. grid(16,32)
// MODE 1: A=Wvt(1024xK), Bt0=xh(4096 rows);  out Vt16 as (b,h,d,t) f16.   grid(32,8)
// MODE 2: A=O16(4096xK), Bt0=Wot;            out f32 row-major (BT x C).  grid(8,32)
template<int MODE>
__global__ __launch_bounds__(256, 2)
void k_gemm(const f16* __restrict__ A, const f16* __restrict__ Bt0, const f16* __restrict__ Bt1,
            void* __restrict__ out0, void* __restrict__ out1) {
  __shared__ __align__(16) f16 As[128 * 64];   // rows of A-tile, XOR-swizzled 16B granules
  __shared__ __align__(16) f16 Bs[128 * 64];   // rows of Bt-tile (n-major)
  const int n0 = blockIdx.x * 128, m0 = blockIdx.y * 128;
  const int tid = threadIdx.x, wave = tid >> 6, lane = tid & 63;
  const int l15 = lane & 15, quad = lane >> 4;
  const int wm = (wave >> 1) * 64, wn = (wave & 1) * 64;
  const f16* Bsrc = Bt0;
  int nb = n0;
  if (MODE == 0 && n0 >= 1024) { Bsrc = Bt1; nb = n0 - 1024; }
  f32x4 acc[4][4] = {};
  const int sr = lane >> 3, sg = lane & 7;
  for (int kt = 0; kt < 16; ++kt) {
    const int k0 = kt * 64;
    __syncthreads();
    #pragma unroll
    for (int p = 0; p < 4; ++p) {
      int r = wave * 32 + p * 8 + sr;
      int gl = sg ^ (r & 7);
      gl_lds16(A    + (size_t)(m0 + r) * 1024 + k0 + gl * 8, &As[(wave * 32 + p * 8) * 64]);
      gl_lds16(Bsrc + (size_t)(nb + r) * 1024 + k0 + gl * 8, &Bs[(wave * 32 + p * 8) * 64]);
    }
    __syncthreads();
    #pragma unroll
    for (int ks = 0; ks < 2; ++ks) {
      f16x8 af[4], bf[4];
      #pragma unroll
      for (int i = 0; i < 4; ++i) {
        int row = wm + i * 16 + l15;
        int gl = (ks * 4 + quad) ^ (row & 7);
        af[i] = *(const f16x8*)&As[row * 64 + gl * 8];
      }
      #pragma unroll
      for (int j = 0; j < 4; ++j) {
        int row = wn + j * 16 + l15;
        int gl = (ks * 4 + quad) ^ (row & 7);
        bf[j] = *(const f16x8*)&Bs[row * 64 + gl * 8];
      }
      #pragma unroll
      for (int i = 0; i < 4; ++i)
        #pragma unroll
        for (int j = 0; j < 4; ++j)
          acc[i][j] = __builtin_amdgcn_mfma_f32_16x16x32_f16(af[i], bf[j], acc[i][j], 0, 0, 0);
    }
  }
  #pragma unroll
  for (int i = 0; i < 4; ++i)
    #pragma unroll
    for (int j = 0; j < 4; ++j)
      #pragma unroll
      for (int r = 0; r < 4; ++r) {
        int m = m0 + wm + i * 16 + quad * 4 + r;
        int n = n0 + wn + j * 16 + l15;
        float v = acc[i][j][r];
        if (MODE == 0) {
          int b = m >> 10, t = m & 1023;
          int nn2 = n & 1023, hh = nn2 >> 6, d = nn2 & 63;
          f16* dst = (n < 1024) ? (f16*)out0 : (f16*)out1;
          dst[(size_t)((b * 16 + hh) * 1024 + t) * 64 + d] = (f16)v;
        } else if (MODE == 1) {
          int hh = m >> 6, d = m & 63;
          int b = n >> 10, t = n & 1023;
          ((f16*)out0)[(size_t)((b * 16 + hh) * 64 + d) * 1024 + t] = (f16)v;
        } else {
          ((float*)out0)[(size_t)m * 1024 + n] = v;
        }
      }
}

// ---------------- fused sparse attention ----------------
// grid = B*H*(T/64) = 1024 blocks, 256 threads (4 waves, each owns 16 q-rows)
__global__ __launch_bounds__(256, 2)
void k_attn(const f16* __restrict__ Q16, const f16* __restrict__ K16, const f16* __restrict__ Vt16,
            const float* __restrict__ imp, const float* __restrict__ temps,
            f16* __restrict__ O16) {
  __shared__ __align__(16) f16 Qs[64 * 64];
  __shared__ __align__(16) f16 Ks[64 * 64];
  __shared__ __align__(16) f16 Vs[64 * 64];   // V^T chunk: rows=d, cols=c
  __shared__ __align__(16) f16 Ps[64 * 64];
  __shared__ __align__(16) float Sl[64 * 68]; // scaled scores, stride 68
  __shared__ unsigned thrL[64];
  __shared__ float psum[4 * 64];

  const int bid = blockIdx.x;
  const int b = bid >> 8, h = (bid >> 4) & 15, qt = bid & 15;
  const int bh = b * 16 + h;
  const int tid = threadIdx.x, wave = tid >> 6, lane = tid & 63;
  const int l15 = lane & 15, quad = lane >> 4;

  // row scale = SCALE/clip(temp) * sigmoid((sigmoid(imp)-0.5)*10), per this wave's rows
  float sc = 0.125f / fminf(fmaxf(temps[bh], 0.1f), 100.0f);
  float rs[4];
  #pragma unroll
  for (int r = 0; r < 4; ++r) {
    int m = wave * 16 + quad * 4 + r;
    int t = qt * 64 + m;
    float is = imp[(size_t)(b * 1024 + t) * 16 + h];
    float s1 = 1.0f / (1.0f + __expf(-is));
    float mwv = 1.0f / (1.0f + __expf(-(s1 - 0.5f) * 10.0f));
    rs[r] = sc * mwv;
  }

  const size_t qoff = ((size_t)bh * 1024 + qt * 64) * 64;
  #pragma unroll
  for (int p = 0; p < 2; ++p) {
    int r = wave * 16 + p * 8 + (lane >> 3);
    int gl = (lane & 7) ^ (r & 7);
    gl_lds16(Q16 + qoff + (size_t)r * 64 + gl * 8, &Qs[(wave * 16 + p * 8) * 64]);
  }

  const size_t kbase = (size_t)bh * 1024 * 64;
  const size_t vbase = (size_t)bh * 64 * 1024;
  f32x4 oacc[4] = {};

  for (int ck = 0; ck < 16; ++ck) {
    __syncthreads();
    #pragma unroll
    for (int p = 0; p < 2; ++p) {
      int r = wave * 16 + p * 8 + (lane >> 3);
      int gl = (lane & 7) ^ (r & 7);
      gl_lds16(K16  + kbase + (size_t)(ck * 64 + r) * 64 + gl * 8, &Ks[(wave * 16 + p * 8) * 64]);
      gl_lds16(Vt16 + vbase + (size_t)r * 1024 + ck * 64 + gl * 8, &Vs[(wave * 16 + p * 8) * 64]);
    }
    __syncthreads();

    // S = Q_strip (16x64) x K^T
    f32x4 sacc[4] = {};
    #pragma unroll
    for (int ks = 0; ks < 2; ++ks) {
      int row = wave * 16 + l15;
      int gl = (ks * 4 + quad) ^ (row & 7);
      f16x8 aq = *(const f16x8*)&Qs[row * 64 + gl * 8];
      #pragma unroll
      for (int j = 0; j < 4; ++j) {
        int rn = j * 16 + l15;
        int gn = (ks * 4 + quad) ^ (rn & 7);
        f16x8 bk = *(const f16x8*)&Ks[rn * 64 + gn * 8];
        sacc[j] = __builtin_amdgcn_mfma_f32_16x16x32_f16(aq, bk, sacc[j], 0, 0, 0);
      }
    }
    #pragma unroll
    for (int j = 0; j < 4; ++j)
      #pragma unroll
      for (int r = 0; r < 4; ++r) {
        int m = wave * 16 + quad * 4 + r;
        Sl[m * 68 + j * 16 + l15] = sacc[j][r] * rs[r];
      }

    // top-32 threshold per row: bitwise ballot-search on top 16 bits of monotone key
    unsigned thr_lane = 0;
    for (int rr = 0; rr < 16; ++rr) {
      int m = wave * 16 + rr;
      float s = Sl[m * 68 + lane];
      unsigned u = __float_as_uint(s);
      unsigned key = u ^ ((unsigned)(((int)u) >> 31) | 0x80000000u);
      unsigned tk = 0;
      #pragma unroll
      for (int bit = 31; bit >= 16; --bit) {
        unsigned cand = tk | (1u << bit);
        unsigned long long bal = __ballot(key >= cand);
        int cnt = __popcll(bal);
        if (cnt >= 32) tk = cand;
      }
      thr_lane = (lane == rr) ? tk : thr_lane;
    }
    if (lane < 16) thrL[wave * 16 + lane] = thr_lane;
    __syncthreads();

    // transposed pass: lane = row, this wave's 16-col slice; m=0 softmax (exact: masked->exp(0)=1)
    unsigned tkey = thrL[lane];
    const int c0 = wave * 16;
    float ev[16];
    float ps = 0.f;
    #pragma unroll
    for (int g = 0; g < 4; ++g) {
      f32x4 sv = *(const f32x4*)&Sl[lane * 68 + c0 + g * 4];
      #pragma unroll
      for (int q = 0; q < 4; ++q) {
        float s = sv[q];
        unsigned u = __float_as_uint(s);
        unsigned key = u ^ ((unsigned)(((int)u) >> 31) | 0x80000000u);
        float e = (key >= tkey) ? __expf(fminf(s, 85.0f)) : 1.0f;
        ev[g * 4 + q] = e;
        ps += e;
      }
    }
    psum[wave * 64 + lane] = ps;
    __syncthreads();

    float den = psum[lane] + psum[64 + lane] + psum[128 + lane] + psum[192 + lane];
    float dinv = 1.0f / den;   // den >= 32, never clips
    #pragma unroll
    for (int i = 0; i < 16; i += 2) {
      int c = c0 + i;
      int gl = (c >> 3) ^ (lane & 7);
      f16x2 pp = { (f16)(ev[i] * dinv), (f16)(ev[i + 1] * dinv) };
      *(f16x2*)&Ps[lane * 64 + gl * 8 + (c & 7)] = pp;
    }
    __syncthreads();

    // O += P (16x64) x V (64x64), V supplied transposed in Vs[d][c]
    #pragma unroll
    for (int ks = 0; ks < 2; ++ks) {
      int row = wave * 16 + l15;
      int gl = (ks * 4 + quad) ^ (row & 7);
      f16x8 ap = *(const f16x8*)&Ps[row * 64 + gl * 8];
      #pragma unroll
      for (int j = 0; j < 4; ++j) {
        int rn = j * 16 + l15;
        int gn = (ks * 4 + quad) ^ (rn & 7);
        f16x8 bv = *(const f16x8*)&Vs[rn * 64 + gn * 8];
        oacc[j] = __builtin_amdgcn_mfma_f32_16x16x32_f16(ap, bv, oacc[j], 0, 0, 0);
      }
    }
  }

  // normalizer == 16 exactly (each chunk softmax sums to 1)
  #pragma unroll
  for (int j = 0; j < 4; ++j)
    #pragma unroll
    for (int r = 0; r < 4; ++r) {
      int m = wave * 16 + quad * 4 + r;
      int t = qt * 64 + m;
      int d = j * 16 + l15;
      O16[(size_t)(b * 1024 + t) * 1024 + h * 64 + d] = (f16)(oacc[j][r] * 0.0625f);
    }
}

extern "C" void kernel_launch(void* const* d_in, const int* in_sizes, int n_in,
                              void* d_out, int out_size, void* d_ws, size_t ws_size,
                              hipStream_t stream) {
  (void)in_sizes; (void)n_in; (void)out_size; (void)ws_size;
  const float* x     = (const float*)d_in[0];
  const float* imp   = (const float*)d_in[1];
  const float* temps = (const float*)d_in[2];
  const float* Wq    = (const float*)d_in[3];
  const float* Wk    = (const float*)d_in[4];
  const float* Wv    = (const float*)d_in[5];
  const float* Wo    = (const float*)d_in[6];
  float* out = (float*)d_out;

  char* w = (char*)d_ws;           // total 48 MB of workspace used
  f16* xh   = (f16*)w; w += (size_t)4096 * 1024 * 2;
  f16* Wqt  = (f16*)w; w += (size_t)1024 * 1024 * 2;
  f16* Wkt  = (f16*)w; w += (size_t)1024 * 1024 * 2;
  f16* Wvt  = (f16*)w; w += (size_t)1024 * 1024 * 2;
  f16* Wot  = (f16*)w; w += (size_t)1024 * 1024 * 2;
  f16* Q16  = (f16*)w; w += (size_t)4096 * 1024 * 2;
  f16* K16  = (f16*)w; w += (size_t)4096 * 1024 * 2;
  f16* Vt16 = (f16*)w; w += (size_t)4096 * 1024 * 2;
  f16* O16  = (f16*)w; w += (size_t)4096 * 1024 * 2;

  k_prep_x<<<dim3(4096), dim3(256), 0, stream>>>(x, xh);
  k_prep_wt<<<dim3(16, 16, 4), dim3(256), 0, stream>>>(Wq, Wk, Wv, Wo, Wqt, Wkt, Wvt, Wot);
  k_gemm<0><<<dim3(16, 32), dim3(256), 0, stream>>>(xh, Wqt, Wkt, (void*)Q16, (void*)K16);
  k_gemm<1><<<dim3(32, 8), dim3(256), 0, stream>>>(Wvt, xh, (const f16*)nullptr, (void*)Vt16, nullptr);
  k_attn<<<dim3(1024), dim3(256), 0, stream>>>(Q16, K16, Vt16, imp, temps, O16);
  k_gemm<2><<<dim3(8, 32), dim3(256), 0, stream>>>(O16, Wot, (const f16*)nullptr, (void*)out, nullptr);
}

// Round 2
// 300.842 us; speedup vs baseline: 1.3997x; 1.3997x over previous
//
#include <hip/hip_runtime.h>
#include <stdint.h>

typedef _Float16 f16;
typedef _Float16 f16x8 __attribute__((ext_vector_type(8)));
typedef _Float16 f16x4 __attribute__((ext_vector_type(4)));
typedef _Float16 f16x2 __attribute__((ext_vector_type(2)));
typedef float f32x4 __attribute__((ext_vector_type(4)));

#define AS1 __attribute__((address_space(1)))
#define AS3 __attribute__((address_space(3)))

__device__ __forceinline__ void gl_lds16(const void* g, void* l) {
  __builtin_amdgcn_global_load_lds((const AS1 uint32_t*)g, (AS3 uint32_t*)l, 16, 0, 0);
}

// sum across a 16-lane DPP row (all lanes get the total); pure VALU pipe
__device__ __forceinline__ unsigned g16sum_u(unsigned v) {
  v += (unsigned)__builtin_amdgcn_update_dpp(0, (int)v, 0x121, 0xf, 0xf, true); // row_ror:1
  v += (unsigned)__builtin_amdgcn_update_dpp(0, (int)v, 0x122, 0xf, 0xf, true); // row_ror:2
  v += (unsigned)__builtin_amdgcn_update_dpp(0, (int)v, 0x124, 0xf, 0xf, true); // row_ror:4
  v += (unsigned)__builtin_amdgcn_update_dpp(0, (int)v, 0x128, 0xf, 0xf, true); // row_ror:8
  return v;
}
__device__ __forceinline__ float g16sum_f(float v) {
  v += __builtin_bit_cast(float, __builtin_amdgcn_update_dpp(0, __builtin_bit_cast(int, v), 0x121, 0xf, 0xf, true));
  v += __builtin_bit_cast(float, __builtin_amdgcn_update_dpp(0, __builtin_bit_cast(int, v), 0x122, 0xf, 0xf, true));
  v += __builtin_bit_cast(float, __builtin_amdgcn_update_dpp(0, __builtin_bit_cast(int, v), 0x124, 0xf, 0xf, true));
  v += __builtin_bit_cast(float, __builtin_amdgcn_update_dpp(0, __builtin_bit_cast(int, v), 0x128, 0xf, 0xf, true));
  return v;
}

// ---------------- prep: x (f32) -> xh (f16) ----------------
__global__ void k_prep_x(const float* __restrict__ x, f16* __restrict__ xh) {
  int i = (blockIdx.x * 256 + threadIdx.x) * 4;
  float4 v = *(const float4*)(x + i);
  f16x4 o = { (f16)v.x, (f16)v.y, (f16)v.z, (f16)v.w };
  *(f16x4*)(xh + i) = o;
}

// ---------------- prep: W (K x N, f32) -> Wt (N x K, f16) ----------------
__global__ void k_prep_wt(const float* __restrict__ Wq, const float* __restrict__ Wk,
                          const float* __restrict__ Wv, const float* __restrict__ Wo,
                          f16* __restrict__ Wqt, f16* __restrict__ Wkt,
                          f16* __restrict__ Wvt, f16* __restrict__ Wot) {
  __shared__ __align__(16) f16 lt[64][72];
  const float* src; f16* dst;
  switch (blockIdx.z) {
    case 0: src = Wq; dst = Wqt; break;
    case 1: src = Wk; dst = Wkt; break;
    case 2: src = Wv; dst = Wvt; break;
    default: src = Wo; dst = Wot; break;
  }
  int n0 = blockIdx.x * 64, k0 = blockIdx.y * 64;
  int t = threadIdx.x;
  int kk = t >> 4;
  int nn = (t & 15) * 4;
  #pragma unroll
  for (int p = 0; p < 4; ++p) {
    int k = kk + p * 16;
    float4 v = *(const float4*)(src + (size_t)(k0 + k) * 1024 + n0 + nn);
    lt[nn + 0][k] = (f16)v.x;
    lt[nn + 1][k] = (f16)v.y;
    lt[nn + 2][k] = (f16)v.z;
    lt[nn + 3][k] = (f16)v.w;
  }
  __syncthreads();
  int row = t >> 2;
  int kp = (t & 3) * 16;
  f16* d = dst + (size_t)(n0 + row) * 1024 + k0 + kp;
  *(f16x8*)d       = *(const f16x8*)&lt[row][kp];
  *(f16x8*)(d + 8) = *(const f16x8*)&lt[row][kp + 8];
}

// ---------------- GEMM (unchanged from round 1) ----------------
template<int MODE>
__global__ __launch_bounds__(256, 2)
void k_gemm(const f16* __restrict__ A, const f16* __restrict__ Bt0, const f16* __restrict__ Bt1,
            void* __restrict__ out0, void* __restrict__ out1) {
  __shared__ __align__(16) f16 As[128 * 64];
  __shared__ __align__(16) f16 Bs[128 * 64];
  const int n0 = blockIdx.x * 128, m0 = blockIdx.y * 128;
  const int tid = threadIdx.x, wave = tid >> 6, lane = tid & 63;
  const int l15 = lane & 15, quad = lane >> 4;
  const int wm = (wave >> 1) * 64, wn = (wave & 1) * 64;
  const f16* Bsrc = Bt0;
  int nb = n0;
  if (MODE == 0 && n0 >= 1024) { Bsrc = Bt1; nb = n0 - 1024; }
  f32x4 acc[4][4] = {};
  const int sr = lane >> 3, sg = lane & 7;
  for (int kt = 0; kt < 16; ++kt) {
    const int k0 = kt * 64;
    __syncthreads();
    #pragma unroll
    for (int p = 0; p < 4; ++p) {
      int r = wave * 32 + p * 8 + sr;
      int gl = sg ^ (r & 7);
      gl_lds16(A    + (size_t)(m0 + r) * 1024 + k0 + gl * 8, &As[(wave * 32 + p * 8) * 64]);
      gl_lds16(Bsrc + (size_t)(nb + r) * 1024 + k0 + gl * 8, &Bs[(wave * 32 + p * 8) * 64]);
    }
    __syncthreads();
    #pragma unroll
    for (int ks = 0; ks < 2; ++ks) {
      f16x8 af[4], bf[4];
      #pragma unroll
      for (int i = 0; i < 4; ++i) {
        int row = wm + i * 16 + l15;
        int gl = (ks * 4 + quad) ^ (row & 7);
        af[i] = *(const f16x8*)&As[row * 64 + gl * 8];
      }
      #pragma unroll
      for (int j = 0; j < 4; ++j) {
        int row = wn + j * 16 + l15;
        int gl = (ks * 4 + quad) ^ (row & 7);
        bf[j] = *(const f16x8*)&Bs[row * 64 + gl * 8];
      }
      #pragma unroll
      for (int i = 0; i < 4; ++i)
        #pragma unroll
        for (int j = 0; j < 4; ++j)
          acc[i][j] = __builtin_amdgcn_mfma_f32_16x16x32_f16(af[i], bf[j], acc[i][j], 0, 0, 0);
    }
  }
  #pragma unroll
  for (int i = 0; i < 4; ++i)
    #pragma unroll
    for (int j = 0; j < 4; ++j)
      #pragma unroll
      for (int r = 0; r < 4; ++r) {
        int m = m0 + wm + i * 16 + quad * 4 + r;
        int n = n0 + wn + j * 16 + l15;
        float v = acc[i][j][r];
        if (MODE == 0) {
          int b = m >> 10, t = m & 1023;
          int nn2 = n & 1023, hh = nn2 >> 6, d = nn2 & 63;
          f16* dst = (n < 1024) ? (f16*)out0 : (f16*)out1;
          dst[(size_t)((b * 16 + hh) * 1024 + t) * 64 + d] = (f16)v;
        } else if (MODE == 1) {
          int hh = m >> 6, d = m & 63;
          int b = n >> 10, t = n & 1023;
          ((f16*)out0)[(size_t)((b * 16 + hh) * 64 + d) * 1024 + t] = (f16)v;
        } else {
          ((float*)out0)[(size_t)m * 1024 + n] = v;
        }
      }
}

// ---------------- fused sparse attention ----------------
// grid = 1024 blocks, 256 threads (4 waves, each owns 16 q-rows).
// Top-32 selection + softmax fully in registers (MFMA C-layout):
// each 16-lane quad-group holds 4 rows x 4 values/lane; bisection counts via
// DPP row_ror butterfly sums. LDS only for Q/K/V tiles + P transpose (32 KB).
__global__ __launch_bounds__(256, 4)
void k_attn(const f16* __restrict__ Q16, const f16* __restrict__ K16, const f16* __restrict__ Vt16,
            const float* __restrict__ imp, const float* __restrict__ temps,
            f16* __restrict__ O16) {
  __shared__ __align__(16) f16 Qs[64 * 64];
  __shared__ __align__(16) f16 Ks[64 * 64];
  __shared__ __align__(16) f16 Vs[64 * 64];   // V^T chunk: rows=d, cols=c
  __shared__ __align__(16) f16 Ps[64 * 64];

  const int bid = blockIdx.x;
  const int b = bid >> 8, h = (bid >> 4) & 15, qt = bid & 15;
  const int bh = b * 16 + h;
  const int tid = threadIdx.x, wave = tid >> 6, lane = tid & 63;
  const int l15 = lane & 15, quad = lane >> 4;

  // per-row scale = SCALE/clip(temp) * sigmoid((sigmoid(imp)-0.5)*10)
  float sc = 0.125f / fminf(fmaxf(temps[bh], 0.1f), 100.0f);
  float rs[4];
  #pragma unroll
  for (int r = 0; r < 4; ++r) {
    int m = wave * 16 + quad * 4 + r;
    int t = qt * 64 + m;
    float is = imp[(size_t)(b * 1024 + t) * 16 + h];
    float s1 = 1.0f / (1.0f + __expf(-is));
    float mwv = 1.0f / (1.0f + __expf(-(s1 - 0.5f) * 10.0f));
    rs[r] = sc * mwv;
  }

  const size_t qoff = ((size_t)bh * 1024 + qt * 64) * 64;
  #pragma unroll
  for (int p = 0; p < 2; ++p) {
    int r = wave * 16 + p * 8 + (lane >> 3);
    int gl = (lane & 7) ^ (r & 7);
    gl_lds16(Q16 + qoff + (size_t)r * 64 + gl * 8, &Qs[(wave * 16 + p * 8) * 64]);
  }

  const size_t kbase = (size_t)bh * 1024 * 64;
  const size_t vbase = (size_t)bh * 64 * 1024;
  f32x4 oacc[4] = {};

  for (int ck = 0; ck < 16; ++ck) {
    __syncthreads();   // B1: everyone done with prev Ks/Vs/Ps
    #pragma unroll
    for (int p = 0; p < 2; ++p) {
      int r = wave * 16 + p * 8 + (lane >> 3);
      int gl = (lane & 7) ^ (r & 7);
      gl_lds16(K16  + kbase + (size_t)(ck * 64 + r) * 64 + gl * 8, &Ks[(wave * 16 + p * 8) * 64]);
      gl_lds16(Vt16 + vbase + (size_t)r * 1024 + ck * 64 + gl * 8, &Vs[(wave * 16 + p * 8) * 64]);
    }
    __syncthreads();   // B2: staging visible

    // ---- S = Q_strip (16x64) x K^T ----
    f32x4 sacc[4] = {};
    #pragma unroll
    for (int ks = 0; ks < 2; ++ks) {
      int row = wave * 16 + l15;
      int gl = (ks * 4 + quad) ^ (row & 7);
      f16x8 aq = *(const f16x8*)&Qs[row * 64 + gl * 8];
      #pragma unroll
      for (int j = 0; j < 4; ++j) {
        int rn = j * 16 + l15;
        int gn = (ks * 4 + quad) ^ (rn & 7);
        f16x8 bk = *(const f16x8*)&Ks[rn * 64 + gn * 8];
        sacc[j] = __builtin_amdgcn_mfma_f32_16x16x32_f16(aq, bk, sacc[j], 0, 0, 0);
      }
    }

    // ---- scale + 16-bit monotone keys (C-layout registers) ----
    float sv[4][4];
    unsigned kh[4][4];
    #pragma unroll
    for (int j = 0; j < 4; ++j)
      #pragma unroll
      for (int r = 0; r < 4; ++r) {
        float x = sacc[j][r] * rs[r];
        sv[j][r] = x;
        unsigned u = __builtin_bit_cast(unsigned, x);
        unsigned key = u ^ ((unsigned)(((int)u) >> 31) | 0x80000000u);
        kh[j][r] = key >> 16;
      }

    // ---- top-32 threshold per row: 16-step count-bisection, row-parallel ----
    unsigned tk[4] = {0u, 0u, 0u, 0u};
    #pragma unroll
    for (int bit = 15; bit >= 0; --bit) {
      unsigned c0 = tk[0] | (1u << bit);
      unsigned c1 = tk[1] | (1u << bit);
      unsigned c2 = tk[2] | (1u << bit);
      unsigned c3 = tk[3] | (1u << bit);
      unsigned n0 = (kh[0][0] >= c0) + (kh[1][0] >= c0) + (kh[2][0] >= c0) + (kh[3][0] >= c0);
      unsigned n1 = (kh[0][1] >= c1) + (kh[1][1] >= c1) + (kh[2][1] >= c1) + (kh[3][1] >= c1);
      unsigned n2 = (kh[0][2] >= c2) + (kh[1][2] >= c2) + (kh[2][2] >= c2) + (kh[3][2] >= c2);
      unsigned n3 = (kh[0][3] >= c3) + (kh[1][3] >= c3) + (kh[2][3] >= c3) + (kh[3][3] >= c3);
      n0 = g16sum_u(n0); n1 = g16sum_u(n1); n2 = g16sum_u(n2); n3 = g16sum_u(n3);
      tk[0] = (n0 >= 32u) ? c0 : tk[0];
      tk[1] = (n1 >= 32u) ? c1 : tk[1];
      tk[2] = (n2 >= 32u) ? c2 : tk[2];
      tk[3] = (n3 >= 32u) ? c3 : tk[3];
    }

    // ---- masked softmax in registers (m=0 exact: masked -> exp(0)=1) ----
    float e[4][4], dinv[4];
    #pragma unroll
    for (int r = 0; r < 4; ++r) {
      #pragma unroll
      for (int j = 0; j < 4; ++j) {
        float x = (kh[j][r] >= tk[r]) ? sv[j][r] : 0.0f;
        e[j][r] = __expf(fminf(x, 85.0f));
      }
      float d = (e[0][r] + e[1][r]) + (e[2][r] + e[3][r]);
      d = g16sum_f(d);
      dinv[r] = __builtin_amdgcn_rcpf(d);
    }

    // ---- P -> f16, transpose via LDS into A-operand layout ----
    #pragma unroll
    for (int j = 0; j < 4; ++j)
      #pragma unroll
      for (int r = 0; r < 4; ++r) {
        int m = wave * 16 + quad * 4 + r;
        int c = j * 16 + l15;
        int gl = (c >> 3) ^ (m & 7);
        Ps[m * 64 + gl * 8 + (c & 7)] = (f16)(e[j][r] * dinv[r]);
      }
    __syncthreads();   // B3: Ps visible

    // ---- O += P (16x64) x V (64x64) ----
    #pragma unroll
    for (int ks = 0; ks < 2; ++ks) {
      int row = wave * 16 + l15;
      int gl = (ks * 4 + quad) ^ (row & 7);
      f16x8 ap = *(const f16x8*)&Ps[row * 64 + gl * 8];
      #pragma unroll
      for (int j = 0; j < 4; ++j) {
        int rn = j * 16 + l15;
        int gn = (ks * 4 + quad) ^ (rn & 7);
        f16x8 bv = *(const f16x8*)&Vs[rn * 64 + gn * 8];
        oacc[j] = __builtin_amdgcn_mfma_f32_16x16x32_f16(ap, bv, oacc[j], 0, 0, 0);
      }
    }
  }

  // normalizer == 16 exactly (each chunk softmax sums to 1)
  #pragma unroll
  for (int j = 0; j < 4; ++j)
    #pragma unroll
    for (int r = 0; r < 4; ++r) {
      int m = wave * 16 + quad * 4 + r;
      int t = qt * 64 + m;
      int d = j * 16 + l15;
      O16[(size_t)(b * 1024 + t) * 1024 + h * 64 + d] = (f16)(oacc[j][r] * 0.0625f);
    }
}

extern "C" void kernel_launch(void* const* d_in, const int* in_sizes, int n_in,
                              void* d_out, int out_size, void* d_ws, size_t ws_size,
                              hipStream_t stream) {
  (void)in_sizes; (void)n_in; (void)out_size; (void)ws_size;
  const float* x     = (const float*)d_in[0];
  const float* imp   = (const float*)d_in[1];
  const float* temps = (const float*)d_in[2];
  const float* Wq    = (const float*)d_in[3];
  const float* Wk    = (const float*)d_in[4];
  const float* Wv    = (const float*)d_in[5];
  const float* Wo    = (const float*)d_in[6];
  float* out = (float*)d_out;

  char* w = (char*)d_ws;
  f16* xh   = (f16*)w; w += (size_t)4096 * 1024 * 2;
  f16* Wqt  = (f16*)w; w += (size_t)1024 * 1024 * 2;
  f16* Wkt  = (f16*)w; w += (size_t)1024 * 1024 * 2;
  f16* Wvt  = (f16*)w; w += (size_t)1024 * 1024 * 2;
  f16* Wot  = (f16*)w; w += (size_t)1024 * 1024 * 2;
  f16* Q16  = (f16*)w; w += (size_t)4096 * 1024 * 2;
  f16* K16  = (f16*)w; w += (size_t)4096 * 1024 * 2;
  f16* Vt16 = (f16*)w; w += (size_t)4096 * 1024 * 2;
  f16* O16  = (f16*)w; w += (size_t)4096 * 1024 * 2;

  k_prep_x<<<dim3(4096), dim3(256), 0, stream>>>(x, xh);
  k_prep_wt<<<dim3(16, 16, 4), dim3(256), 0, stream>>>(Wq, Wk, Wv, Wo, Wqt, Wkt, Wvt, Wot);
  k_gemm<0><<<dim3(16, 32), dim3(256), 0, stream>>>(xh, Wqt, Wkt, (void*)Q16, (void*)K16);
  k_gemm<1><<<dim3(32, 8), dim3(256), 0, stream>>>(Wvt, xh, (const f16*)nullptr, (void*)Vt16, nullptr);
  k_attn<<<dim3(1024), dim3(256), 0, stream>>>(Q16, K16, Vt16, imp, temps, O16);
  k_gemm<2><<<dim3(8, 32), dim3(256), 0, stream>>>(O16, Wot, (const f16*)nullptr, (void*)out, nullptr);
}

// Round 3
// 280.356 us; speedup vs baseline: 1.5020x; 1.0731x over previous
//
#include <hip/hip_runtime.h>
#include <stdint.h>

typedef _Float16 f16;
typedef _Float16 f16x8 __attribute__((ext_vector_type(8)));
typedef _Float16 f16x4 __attribute__((ext_vector_type(4)));
typedef _Float16 f16x2 __attribute__((ext_vector_type(2)));
typedef float f32x4 __attribute__((ext_vector_type(4)));

#define AS1 __attribute__((address_space(1)))
#define AS3 __attribute__((address_space(3)))

#if __has_builtin(__builtin_amdgcn_exp2f)
#define EXP2(x) __builtin_amdgcn_exp2f(x)
#else
#define EXP2(x) exp2f(x)
#endif

__device__ __forceinline__ void gl_lds16(const void* g, void* l) {
  __builtin_amdgcn_global_load_lds((const AS1 uint32_t*)g, (AS3 uint32_t*)l, 16, 0, 0);
}

// sum across a 16-lane DPP row (all lanes get the total); pure VALU pipe
__device__ __forceinline__ unsigned dpp16sum_u(unsigned v) {
  v += (unsigned)__builtin_amdgcn_update_dpp(0, (int)v, 0x121, 0xf, 0xf, true);
  v += (unsigned)__builtin_amdgcn_update_dpp(0, (int)v, 0x122, 0xf, 0xf, true);
  v += (unsigned)__builtin_amdgcn_update_dpp(0, (int)v, 0x124, 0xf, 0xf, true);
  v += (unsigned)__builtin_amdgcn_update_dpp(0, (int)v, 0x128, 0xf, 0xf, true);
  return v;
}
__device__ __forceinline__ float g16sum_f(float v) {
  v += __builtin_bit_cast(float, __builtin_amdgcn_update_dpp(0, __builtin_bit_cast(int, v), 0x121, 0xf, 0xf, true));
  v += __builtin_bit_cast(float, __builtin_amdgcn_update_dpp(0, __builtin_bit_cast(int, v), 0x122, 0xf, 0xf, true));
  v += __builtin_bit_cast(float, __builtin_amdgcn_update_dpp(0, __builtin_bit_cast(int, v), 0x124, 0xf, 0xf, true));
  v += __builtin_bit_cast(float, __builtin_amdgcn_update_dpp(0, __builtin_bit_cast(int, v), 0x128, 0xf, 0xf, true));
  return v;
}

// ---------------- prep: x (f32) -> xh (f16) ----------------
__global__ void k_prep_x(const float* __restrict__ x, f16* __restrict__ xh) {
  int i = (blockIdx.x * 256 + threadIdx.x) * 4;
  float4 v = *(const float4*)(x + i);
  f16x4 o = { (f16)v.x, (f16)v.y, (f16)v.z, (f16)v.w };
  *(f16x4*)(xh + i) = o;
}

// ---------------- prep: W (K x N, f32) -> Wt (N x K, f16) ----------------
__global__ void k_prep_wt(const float* __restrict__ Wq, const float* __restrict__ Wk,
                          const float* __restrict__ Wv, const float* __restrict__ Wo,
                          f16* __restrict__ Wqt, f16* __restrict__ Wkt,
                          f16* __restrict__ Wvt, f16* __restrict__ Wot) {
  __shared__ __align__(16) f16 lt[64][72];
  const float* src; f16* dst;
  switch (blockIdx.z) {
    case 0: src = Wq; dst = Wqt; break;
    case 1: src = Wk; dst = Wkt; break;
    case 2: src = Wv; dst = Wvt; break;
    default: src = Wo; dst = Wot; break;
  }
  int n0 = blockIdx.x * 64, k0 = blockIdx.y * 64;
  int t = threadIdx.x;
  int kk = t >> 4;
  int nn = (t & 15) * 4;
  #pragma unroll
  for (int p = 0; p < 4; ++p) {
    int k = kk + p * 16;
    float4 v = *(const float4*)(src + (size_t)(k0 + k) * 1024 + n0 + nn);
    lt[nn + 0][k] = (f16)v.x;
    lt[nn + 1][k] = (f16)v.y;
    lt[nn + 2][k] = (f16)v.z;
    lt[nn + 3][k] = (f16)v.w;
  }
  __syncthreads();
  int row = t >> 2;
  int kp = (t & 3) * 16;
  f16* d = dst + (size_t)(n0 + row) * 1024 + k0 + kp;
  *(f16x8*)d       = *(const f16x8*)&lt[row][kp];
  *(f16x8*)(d + 8) = *(const f16x8*)&lt[row][kp + 8];
}

// ---------------- GEMM: C(TMxN128 per block) = A * Bt^T ----------------
// MODE 0, TM=128: A=xh(4096xK), Bt0/1/2=Wqt/Wkt/Wvt; N=3072; grid(24,32).
//   out0=Q16,out1=K16 as (b,h,t,d); out2=Vt16 TRANSPOSED (b,h,d,t), f16x4 stores.
// MODE 2, TM=64:  A=O16(4096xK), Bt0=Wot; out0 = f32 row-major (BT x C). grid(8,64).
template<int MODE, int TM>
__global__ __launch_bounds__(256, 2)
void k_gemm(const f16* __restrict__ A, const f16* __restrict__ Bt0,
            const f16* __restrict__ Bt1, const f16* __restrict__ Bt2,
            void* __restrict__ out0, void* __restrict__ out1, void* __restrict__ out2) {
  __shared__ __align__(16) f16 As[TM * 64];
  __shared__ __align__(16) f16 Bs[128 * 64];
  const int n0 = blockIdx.x * 128, m0 = blockIdx.y * TM;
  const int tid = threadIdx.x, wave = tid >> 6, lane = tid & 63;
  const int l15 = lane & 15, quad = lane >> 4;
  const int wm = (wave >> 1) * (TM / 2), wn = (wave & 1) * 64;
  constexpr int NI = TM / 32;    // A-frags per wave
  constexpr int PA = TM / 32;    // A staging instrs per wave
  const f16* Bsrc = Bt0;
  int nb = n0;
  if (MODE == 0) {
    if (n0 >= 2048)      { Bsrc = Bt2; nb = n0 - 2048; }
    else if (n0 >= 1024) { Bsrc = Bt1; nb = n0 - 1024; }
  }
  f32x4 acc[NI][4] = {};
  const int sr = lane >> 3, sg = lane & 7;
  for (int kt = 0; kt < 16; ++kt) {
    const int k0 = kt * 64;
    __syncthreads();
    #pragma unroll
    for (int p = 0; p < PA; ++p) {
      int r = wave * (TM / 4) + p * 8 + sr;
      int gl = sg ^ (r & 7);
      gl_lds16(A + (size_t)(m0 + r) * 1024 + k0 + gl * 8, &As[(wave * (TM / 4) + p * 8) * 64]);
    }
    #pragma unroll
    for (int p = 0; p < 4; ++p) {
      int r = wave * 32 + p * 8 + sr;
      int gl = sg ^ (r & 7);
      gl_lds16(Bsrc + (size_t)(nb + r) * 1024 + k0 + gl * 8, &Bs[(wave * 32 + p * 8) * 64]);
    }
    __syncthreads();
    #pragma unroll
    for (int ks = 0; ks < 2; ++ks) {
      f16x8 af[NI], bf[4];
      #pragma unroll
      for (int i = 0; i < NI; ++i) {
        int row = wm + i * 16 + l15;
        int gl = (ks * 4 + quad) ^ (row & 7);
        af[i] = *(const f16x8*)&As[row * 64 + gl * 8];
      }
      #pragma unroll
      for (int j = 0; j < 4; ++j) {
        int row = wn + j * 16 + l15;
        int gl = (ks * 4 + quad) ^ (row & 7);
        bf[j] = *(const f16x8*)&Bs[row * 64 + gl * 8];
      }
      #pragma unroll
      for (int i = 0; i < NI; ++i)
        #pragma unroll
        for (int j = 0; j < 4; ++j)
          acc[i][j] = __builtin_amdgcn_mfma_f32_16x16x32_f16(af[i], bf[j], acc[i][j], 0, 0, 0);
    }
  }

  if (MODE == 0) {
    if (n0 < 2048) {
      f16* dst = (n0 < 1024) ? (f16*)out0 : (f16*)out1;
      #pragma unroll
      for (int i = 0; i < NI; ++i)
        #pragma unroll
        for (int j = 0; j < 4; ++j)
          #pragma unroll
          for (int r = 0; r < 4; ++r) {
            int m = m0 + wm + i * 16 + quad * 4 + r;
            int n = n0 + wn + j * 16 + l15;
            int b = m >> 10, t = m & 1023;
            int nn2 = n & 1023, hh = nn2 >> 6, d = nn2 & 63;
            dst[(size_t)((b * 16 + hh) * 1024 + t) * 64 + d] = (f16)acc[i][j][r];
          }
    } else {
      // V: write transposed (b,h,d,t) with f16x4 along t
      #pragma unroll
      for (int i = 0; i < NI; ++i)
        #pragma unroll
        for (int j = 0; j < 4; ++j) {
          int mb = m0 + wm + i * 16 + quad * 4;
          int b = mb >> 10, t = mb & 1023;
          int n = n0 + wn + j * 16 + l15;
          int nn2 = n & 1023, hh = nn2 >> 6, d = nn2 & 63;
          f16x4 vv = { (f16)acc[i][j][0], (f16)acc[i][j][1], (f16)acc[i][j][2], (f16)acc[i][j][3] };
          *(f16x4*)((f16*)out2 + ((size_t)(b * 16 + hh) * 64 + d) * 1024 + t) = vv;
        }
    }
  } else {
    #pragma unroll
    for (int i = 0; i < NI; ++i)
      #pragma unroll
      for (int j = 0; j < 4; ++j)
        #pragma unroll
        for (int r = 0; r < 4; ++r) {
          int m = m0 + wm + i * 16 + quad * 4 + r;
          int n = n0 + wn + j * 16 + l15;
          ((float*)out0)[(size_t)m * 1024 + n] = acc[i][j][r];
        }
  }
}

// ---------------- fused sparse attention ----------------
// 1024 blocks x 256 threads (4 waves x 16 q-rows). Selection/softmax in
// registers (C-layout); counts byte-packed (4 rows/reg) -> 4 DPP per step;
// SWAR >=32 test; exp2 with log2e folded into row scale. 2 barriers/chunk
// (P-tile is per-wave private -> no barrier between P write and PV read).
__global__ __launch_bounds__(256, 4)
void k_attn(const f16* __restrict__ Q16, const f16* __restrict__ K16, const f16* __restrict__ Vt16,
            const float* __restrict__ imp, const float* __restrict__ temps,
            f16* __restrict__ O16) {
  __shared__ __align__(16) f16 Qs[64 * 64];
  __shared__ __align__(16) f16 Ks[64 * 64];
  __shared__ __align__(16) f16 Vs[64 * 64];   // V^T chunk: rows=d, cols=c
  __shared__ __align__(16) f16 Ps[64 * 64];

  const int bid = blockIdx.x;
  const int b = bid >> 8, h = (bid >> 4) & 15, qt = bid & 15;
  const int bh = b * 16 + h;
  const int tid = threadIdx.x, wave = tid >> 6, lane = tid & 63;
  const int l15 = lane & 15, quad = lane >> 4;

  // row scale * log2(e): scores scaled by a positive constant -> selection order
  // unchanged; exp(s) == exp2(s'') directly via v_exp_f32.
  float sc = (0.125f * 1.44269504088896340736f) / fminf(fmaxf(temps[bh], 0.1f), 100.0f);
  float rs[4];
  #pragma unroll
  for (int r = 0; r < 4; ++r) {
    int m = wave * 16 + quad * 4 + r;
    int t = qt * 64 + m;
    float is = imp[(size_t)(b * 1024 + t) * 16 + h];
    float s1 = 1.0f / (1.0f + __expf(-is));
    float mwv = 1.0f / (1.0f + __expf(-(s1 - 0.5f) * 10.0f));
    rs[r] = sc * mwv;
  }

  const size_t qoff = ((size_t)bh * 1024 + qt * 64) * 64;
  #pragma unroll
  for (int p = 0; p < 2; ++p) {
    int r = wave * 16 + p * 8 + (lane >> 3);
    int gl = (lane & 7) ^ (r & 7);
    gl_lds16(Q16 + qoff + (size_t)r * 64 + gl * 8, &Qs[(wave * 16 + p * 8) * 64]);
  }

  const size_t kbase = (size_t)bh * 1024 * 64;
  const size_t vbase = (size_t)bh * 64 * 1024;
  f32x4 oacc[4] = {};

  for (int ck = 0; ck < 16; ++ck) {
    __syncthreads();   // B1: all waves done reading prev Ks/Vs
    #pragma unroll
    for (int p = 0; p < 2; ++p) {
      int r = wave * 16 + p * 8 + (lane >> 3);
      int gl = (lane & 7) ^ (r & 7);
      gl_lds16(K16  + kbase + (size_t)(ck * 64 + r) * 64 + gl * 8, &Ks[(wave * 16 + p * 8) * 64]);
      gl_lds16(Vt16 + vbase + (size_t)r * 1024 + ck * 64 + gl * 8, &Vs[(wave * 16 + p * 8) * 64]);
    }
    __syncthreads();   // B2: staging visible

    // ---- S = Q_strip (16x64) x K^T ----
    f32x4 sacc[4] = {};
    #pragma unroll
    for (int ks = 0; ks < 2; ++ks) {
      int row = wave * 16 + l15;
      int gl = (ks * 4 + quad) ^ (row & 7);
      f16x8 aq = *(const f16x8*)&Qs[row * 64 + gl * 8];
      #pragma unroll
      for (int j = 0; j < 4; ++j) {
        int rn = j * 16 + l15;
        int gn = (ks * 4 + quad) ^ (rn & 7);
        f16x8 bk = *(const f16x8*)&Ks[rn * 64 + gn * 8];
        sacc[j] = __builtin_amdgcn_mfma_f32_16x16x32_f16(aq, bk, sacc[j], 0, 0, 0);
      }
    }

    // ---- scale + full-32-bit monotone keys (C-layout registers) ----
    float sv[4][4];
    unsigned key[4][4];
    #pragma unroll
    for (int j = 0; j < 4; ++j)
      #pragma unroll
      for (int r = 0; r < 4; ++r) {
        float x = sacc[j][r] * rs[r];
        sv[j][r] = x;
        unsigned u = __builtin_bit_cast(unsigned, x);
        key[j][r] = u ^ ((unsigned)(((int)u) >> 31) | 0x80000000u);
      }

    // ---- top-32 threshold per row: 16-step bisection on key bits 31..16,
    //      4 row-counts byte-packed -> one DPP butterfly per step ----
    unsigned tk0 = 0u, tk1 = 0u, tk2 = 0u, tk3 = 0u;
    #pragma unroll
    for (int bit = 15; bit >= 0; --bit) {
      const unsigned bp = 1u << (16 + bit);
      unsigned c0 = tk0 | bp, c1 = tk1 | bp, c2 = tk2 | bp, c3 = tk3 | bp;
      unsigned n0 = (key[0][0] >= c0) + (key[1][0] >= c0) + (key[2][0] >= c0) + (key[3][0] >= c0);
      unsigned n1 = (key[0][1] >= c1) + (key[1][1] >= c1) + (key[2][1] >= c1) + (key[3][1] >= c1);
      unsigned n2 = (key[0][2] >= c2) + (key[1][2] >= c2) + (key[2][2] >= c2) + (key[3][2] >= c2);
      unsigned n3 = (key[0][3] >= c3) + (key[1][3] >= c3) + (key[2][3] >= c3) + (key[3][3] >= c3);
      unsigned pk = n0 + (n1 << 8) + (n2 << 16) + (n3 << 24);
      pk = dpp16sum_u(pk);
      unsigned ge = ((pk | 0x80808080u) - 0x20202020u) & 0x80808080u;
      tk0 |= ((ge >> 7)  & 1u) << (16 + bit);
      tk1 |= ((ge >> 15) & 1u) << (16 + bit);
      tk2 |= ((ge >> 23) & 1u) << (16 + bit);
      tk3 |= (ge >> 31)        << (16 + bit);
    }
    const unsigned tkr[4] = { tk0, tk1, tk2, tk3 };

    // ---- masked softmax (m=0 exact: masked -> exp2(0)=1) ----
    float e[4][4], dinv[4];
    #pragma unroll
    for (int r = 0; r < 4; ++r) {
      #pragma unroll
      for (int j = 0; j < 4; ++j) {
        float x = (key[j][r] >= tkr[r]) ? fminf(sv[j][r], 122.0f) : 0.0f;
        e[j][r] = EXP2(x);
      }
      float d = (e[0][r] + e[1][r]) + (e[2][r] + e[3][r]);
      d = g16sum_f(d);
      dinv[r] = __builtin_amdgcn_rcpf(d);   // d >= 32, exact-safe
    }

    // ---- P -> f16 into A-operand layout (per-wave-private region) ----
    #pragma unroll
    for (int j = 0; j < 4; ++j)
      #pragma unroll
      for (int r = 0; r < 4; ++r) {
        int m = wave * 16 + quad * 4 + r;
        int c = j * 16 + l15;
        int gl = (c >> 3) ^ (m & 7);
        Ps[m * 64 + gl * 8 + (c & 7)] = (f16)(e[j][r] * dinv[r]);
      }
    // no barrier: this wave reads exactly the rows it wrote (lgkmcnt suffices)

    // ---- O += P (16x64) x V (64x64) ----
    #pragma unroll
    for (int ks = 0; ks < 2; ++ks) {
      int row = wave * 16 + l15;
      int gl = (ks * 4 + quad) ^ (row & 7);
      f16x8 ap = *(const f16x8*)&Ps[row * 64 + gl * 8];
      #pragma unroll
      for (int j = 0; j < 4; ++j) {
        int rn = j * 16 + l15;
        int gn = (ks * 4 + quad) ^ (rn & 7);
        f16x8 bv = *(const f16x8*)&Vs[rn * 64 + gn * 8];
        oacc[j] = __builtin_amdgcn_mfma_f32_16x16x32_f16(ap, bv, oacc[j], 0, 0, 0);
      }
    }
  }

  // normalizer == 16 exactly (each chunk softmax sums to 1)
  #pragma unroll
  for (int j = 0; j < 4; ++j)
    #pragma unroll
    for (int r = 0; r < 4; ++r) {
      int m = wave * 16 + quad * 4 + r;
      int t = qt * 64 + m;
      int d = j * 16 + l15;
      O16[(size_t)(b * 1024 + t) * 1024 + h * 64 + d] = (f16)(oacc[j][r] * 0.0625f);
    }
}

extern "C" void kernel_launch(void* const* d_in, const int* in_sizes, int n_in,
                              void* d_out, int out_size, void* d_ws, size_t ws_size,
                              hipStream_t stream) {
  (void)in_sizes; (void)n_in; (void)out_size; (void)ws_size;
  const float* x     = (const float*)d_in[0];
  const float* imp   = (const float*)d_in[1];
  const float* temps = (const float*)d_in[2];
  const float* Wq    = (const float*)d_in[3];
  const float* Wk    = (const float*)d_in[4];
  const float* Wv    = (const float*)d_in[5];
  const float* Wo    = (const float*)d_in[6];
  float* out = (float*)d_out;

  char* w = (char*)d_ws;   // 48 MB
  f16* xh   = (f16*)w; w += (size_t)4096 * 1024 * 2;
  f16* Wqt  = (f16*)w; w += (size_t)1024 * 1024 * 2;
  f16* Wkt  = (f16*)w; w += (size_t)1024 * 1024 * 2;
  f16* Wvt  = (f16*)w; w += (size_t)1024 * 1024 * 2;
  f16* Wot  = (f16*)w; w += (size_t)1024 * 1024 * 2;
  f16* Q16  = (f16*)w; w += (size_t)4096 * 1024 * 2;
  f16* K16  = (f16*)w; w += (size_t)4096 * 1024 * 2;
  f16* Vt16 = (f16*)w; w += (size_t)4096 * 1024 * 2;
  f16* O16  = (f16*)w; w += (size_t)4096 * 1024 * 2;

  k_prep_x<<<dim3(4096), dim3(256), 0, stream>>>(x, xh);
  k_prep_wt<<<dim3(16, 16, 4), dim3(256), 0, stream>>>(Wq, Wk, Wv, Wo, Wqt, Wkt, Wvt, Wot);
  k_gemm<0, 128><<<dim3(24, 32), dim3(256), 0, stream>>>(xh, Wqt, Wkt, Wvt,
                                                         (void*)Q16, (void*)K16, (void*)Vt16);
  k_attn<<<dim3(1024), dim3(256), 0, stream>>>(Q16, K16, Vt16, imp, temps, O16);
  k_gemm<2, 64><<<dim3(8, 64), dim3(256), 0, stream>>>(O16, Wot, nullptr, nullptr,
                                                       (void*)out, nullptr, nullptr);
}

// Round 4
// 269.810 us; speedup vs baseline: 1.5607x; 1.0391x over previous
//
#include <hip/hip_runtime.h>
#include <stdint.h>

typedef _Float16 f16;
typedef _Float16 f16x8 __attribute__((ext_vector_type(8)));
typedef _Float16 f16x4 __attribute__((ext_vector_type(4)));
typedef float f32x4 __attribute__((ext_vector_type(4)));

#define AS1 __attribute__((address_space(1)))
#define AS3 __attribute__((address_space(3)))

#if __has_builtin(__builtin_amdgcn_exp2f)
#define EXP2(x) __builtin_amdgcn_exp2f(x)
#else
#define EXP2(x) exp2f(x)
#endif

__device__ __forceinline__ void gl_lds16(const void* g, void* l) {
  __builtin_amdgcn_global_load_lds((const AS1 uint32_t*)g, (AS3 uint32_t*)l, 16, 0, 0);
}

__device__ __forceinline__ unsigned dpp16sum_u(unsigned v) {
  v += (unsigned)__builtin_amdgcn_update_dpp(0, (int)v, 0x121, 0xf, 0xf, true);
  v += (unsigned)__builtin_amdgcn_update_dpp(0, (int)v, 0x122, 0xf, 0xf, true);
  v += (unsigned)__builtin_amdgcn_update_dpp(0, (int)v, 0x124, 0xf, 0xf, true);
  v += (unsigned)__builtin_amdgcn_update_dpp(0, (int)v, 0x128, 0xf, 0xf, true);
  return v;
}
__device__ __forceinline__ float g16sum_f(float v) {
  v += __builtin_bit_cast(float, __builtin_amdgcn_update_dpp(0, __builtin_bit_cast(int, v), 0x121, 0xf, 0xf, true));
  v += __builtin_bit_cast(float, __builtin_amdgcn_update_dpp(0, __builtin_bit_cast(int, v), 0x122, 0xf, 0xf, true));
  v += __builtin_bit_cast(float, __builtin_amdgcn_update_dpp(0, __builtin_bit_cast(int, v), 0x124, 0xf, 0xf, true));
  v += __builtin_bit_cast(float, __builtin_amdgcn_update_dpp(0, __builtin_bit_cast(int, v), 0x128, 0xf, 0xf, true));
  return v;
}

// ---------- fused prep: z=0..3 -> W transpose+cvt; z=4 -> x f32->f16 ----------
__global__ void k_prep(const float* __restrict__ x,
                       const float* __restrict__ Wq, const float* __restrict__ Wk,
                       const float* __restrict__ Wv, const float* __restrict__ Wo,
                       f16* __restrict__ xh,
                       f16* __restrict__ Wqt, f16* __restrict__ Wkt,
                       f16* __restrict__ Wvt, f16* __restrict__ Wot) {
  __shared__ __align__(16) f16 lt[64][72];
  const int t = threadIdx.x;
  if (blockIdx.z == 4) {
    int bid2 = blockIdx.y * 16 + blockIdx.x;   // 0..255
    #pragma unroll 4
    for (int it = 0; it < 16; ++it) {
      int i = ((bid2 * 16 + it) * 256 + t) * 4;
      float4 v = *(const float4*)(x + i);
      f16x4 o = { (f16)v.x, (f16)v.y, (f16)v.z, (f16)v.w };
      *(f16x4*)(xh + i) = o;
    }
    return;
  }
  const float* src; f16* dst;
  switch (blockIdx.z) {
    case 0: src = Wq; dst = Wqt; break;
    case 1: src = Wk; dst = Wkt; break;
    case 2: src = Wv; dst = Wvt; break;
    default: src = Wo; dst = Wot; break;
  }
  int n0 = blockIdx.x * 64, k0 = blockIdx.y * 64;
  int kk = t >> 4;
  int nn = (t & 15) * 4;
  #pragma unroll
  for (int p = 0; p < 4; ++p) {
    int k = kk + p * 16;
    float4 v = *(const float4*)(src + (size_t)(k0 + k) * 1024 + n0 + nn);
    lt[nn + 0][k] = (f16)v.x;
    lt[nn + 1][k] = (f16)v.y;
    lt[nn + 2][k] = (f16)v.z;
    lt[nn + 3][k] = (f16)v.w;
  }
  __syncthreads();
  int row = t >> 2;
  int kp = (t & 3) * 16;
  f16* d = dst + (size_t)(n0 + row) * 1024 + k0 + kp;
  *(f16x8*)d       = *(const f16x8*)&lt[row][kp];
  *(f16x8*)(d + 8) = *(const f16x8*)&lt[row][kp + 8];
}

// ---------------- GEMM: C(TMxN128 per block) = A * Bt^T ----------------
// MODE 0, TM=128: A=xh(4096xK), Bt0/1/2=Wqt/Wkt/Wvt; N=3072; grid(24,32).
//   Q16,K16 (b,h,t,d) via LDS-transposed f16x8 stores; Vt16 (b,h,d,t) f16x4.
// MODE 2, TM=64:  A=O16(4096xK), Bt0=Wot; out0 = f32 row-major. grid(8,64).
template<int MODE, int TM>
__global__ __launch_bounds__(256, 2)
void k_gemm(const f16* __restrict__ A, const f16* __restrict__ Bt0,
            const f16* __restrict__ Bt1, const f16* __restrict__ Bt2,
            void* __restrict__ out0, void* __restrict__ out1, void* __restrict__ out2) {
  __shared__ __align__(16) f16 As[TM * 64];
  __shared__ __align__(16) f16 Bs[128 * 64];
  __shared__ __align__(16) f16 EP[(MODE == 0) ? 4 * 64 * 72 : 4];  // epilogue arena
  const int n0 = blockIdx.x * 128, m0 = blockIdx.y * TM;
  const int tid = threadIdx.x, wave = tid >> 6, lane = tid & 63;
  const int l15 = lane & 15, quad = lane >> 4;
  const int wm = (wave >> 1) * (TM / 2), wn = (wave & 1) * 64;
  constexpr int NI = TM / 32;
  constexpr int PA = TM / 32;
  const f16* Bsrc = Bt0;
  int nb = n0;
  if (MODE == 0) {
    if (n0 >= 2048)      { Bsrc = Bt2; nb = n0 - 2048; }
    else if (n0 >= 1024) { Bsrc = Bt1; nb = n0 - 1024; }
  }
  f32x4 acc[NI][4] = {};
  const int sr = lane >> 3, sg = lane & 7;
  const int gl = sg ^ sr;            // (r&7)==sr for all staging rows
  // hoisted staging pointers (advance +64 per k-tile)
  const f16* ap[PA];
  const f16* bp[4];
  #pragma unroll
  for (int p = 0; p < PA; ++p)
    ap[p] = A + (size_t)(m0 + wave * (TM / 4) + p * 8 + sr) * 1024 + gl * 8;
  #pragma unroll
  for (int p = 0; p < 4; ++p)
    bp[p] = Bsrc + (size_t)(nb + wave * 32 + p * 8 + sr) * 1024 + gl * 8;

  for (int kt = 0; kt < 16; ++kt) {
    __syncthreads();
    #pragma unroll
    for (int p = 0; p < PA; ++p) {
      gl_lds16(ap[p], &As[(wave * (TM / 4) + p * 8) * 64]);
      ap[p] += 64;
    }
    #pragma unroll
    for (int p = 0; p < 4; ++p) {
      gl_lds16(bp[p], &Bs[(wave * 32 + p * 8) * 64]);
      bp[p] += 64;
    }
    __syncthreads();
    #pragma unroll
    for (int ks = 0; ks < 2; ++ks) {
      f16x8 af[NI], bf[4];
      #pragma unroll
      for (int i = 0; i < NI; ++i) {
        int row = wm + i * 16 + l15;
        int g2 = (ks * 4 + quad) ^ (row & 7);
        af[i] = *(const f16x8*)&As[row * 64 + g2 * 8];
      }
      #pragma unroll
      for (int j = 0; j < 4; ++j) {
        int row = wn + j * 16 + l15;
        int g2 = (ks * 4 + quad) ^ (row & 7);
        bf[j] = *(const f16x8*)&Bs[row * 64 + g2 * 8];
      }
      #pragma unroll
      for (int i = 0; i < NI; ++i)
        #pragma unroll
        for (int j = 0; j < 4; ++j)
          acc[i][j] = __builtin_amdgcn_mfma_f32_16x16x32_f16(af[i], bf[j], acc[i][j], 0, 0, 0);
    }
  }

  if (MODE == 0) {
    if (n0 < 2048) {
      // LDS transpose (per-wave-private arena, stride 72, no barrier) -> f16x8 stores
      f16* ep = &EP[wave * 64 * 72];
      #pragma unroll
      for (int i = 0; i < NI; ++i)
        #pragma unroll
        for (int j = 0; j < 4; ++j)
          #pragma unroll
          for (int r = 0; r < 4; ++r)
            ep[(i * 16 + quad * 4 + r) * 72 + j * 16 + l15] = (f16)acc[i][j][r];
      f16* dst = (n0 < 1024) ? (f16*)out0 : (f16*)out1;
      const int hh = ((n0 + wn) & 1023) >> 6;
      const int r8 = lane >> 3, cg = lane & 7;
      #pragma unroll
      for (int it = 0; it < 8; ++it) {
        int row = it * 8 + r8;
        f16x8 vv = *(const f16x8*)&ep[row * 72 + cg * 8];
        int m = m0 + wm + row;
        int b = m >> 10, t = m & 1023;
        *(f16x8*)&dst[(size_t)((b * 16 + hh) * 1024 + t) * 64 + cg * 8] = vv;
      }
    } else {
      // V: write transposed (b,h,d,t), f16x4 along t
      #pragma unroll
      for (int i = 0; i < NI; ++i)
        #pragma unroll
        for (int j = 0; j < 4; ++j) {
          int mb = m0 + wm + i * 16 + quad * 4;
          int b = mb >> 10, t = mb & 1023;
          int n = n0 + wn + j * 16 + l15;
          int nn2 = n & 1023, hh = nn2 >> 6, d = nn2 & 63;
          f16x4 vv = { (f16)acc[i][j][0], (f16)acc[i][j][1], (f16)acc[i][j][2], (f16)acc[i][j][3] };
          *(f16x4*)((f16*)out2 + ((size_t)(b * 16 + hh) * 64 + d) * 1024 + t) = vv;
        }
    }
  } else {
    #pragma unroll
    for (int i = 0; i < NI; ++i)
      #pragma unroll
      for (int j = 0; j < 4; ++j)
        #pragma unroll
        for (int r = 0; r < 4; ++r) {
          int m = m0 + wm + i * 16 + quad * 4 + r;
          int n = n0 + wn + j * 16 + l15;
          ((float*)out0)[(size_t)m * 1024 + n] = acc[i][j][r];
        }
  }
}

// ---------------- fused sparse attention (half the chunks per block) ----------------
// grid 2048: bid=blockIdx&1023 -> (b,h,qt); half=blockIdx>>10 -> chunks [8h,8h+8).
// Bias-key selection: key = bits(med3(s,-60,60)+3072) — all keys in one octave,
// uint-monotone; bisect mantissa bits 22..7. Counts byte-packed, 4 DPP/step.
__global__ __launch_bounds__(256, 4)
void k_attn(const f16* __restrict__ Q16, const f16* __restrict__ K16, const f16* __restrict__ Vt16,
            const float* __restrict__ imp, const float* __restrict__ temps,
            f16* __restrict__ part0, f16* __restrict__ part1) {
  __shared__ __align__(16) f16 Qs[64 * 64];
  __shared__ __align__(16) f16 Ks[64 * 64];
  __shared__ __align__(16) f16 Vs[64 * 64];
  __shared__ __align__(16) f16 Ps[64 * 64];

  const int bid = blockIdx.x & 1023;
  const int half = blockIdx.x >> 10;
  const int b = bid >> 8, h = (bid >> 4) & 15, qt = bid & 15;
  const int bh = b * 16 + h;
  const int tid = threadIdx.x, wave = tid >> 6, lane = tid & 63;
  const int l15 = lane & 15, quad = lane >> 4;

  float sc = (0.125f * 1.44269504088896340736f) / fminf(fmaxf(temps[bh], 0.1f), 100.0f);
  float rs[4];
  #pragma unroll
  for (int r = 0; r < 4; ++r) {
    int m = wave * 16 + quad * 4 + r;
    int t = qt * 64 + m;
    float is = imp[(size_t)(b * 1024 + t) * 16 + h];
    float s1 = 1.0f / (1.0f + __expf(-is));
    float mwv = 1.0f / (1.0f + __expf(-(s1 - 0.5f) * 10.0f));
    rs[r] = sc * mwv;
  }

  const int sr = lane >> 3, sg = lane & 7;
  const int gls = sg ^ sr;                 // staging swizzle, uniform per lane
  const size_t qoff = ((size_t)bh * 1024 + qt * 64) * 64;
  gl_lds16(Q16 + qoff + (size_t)(wave * 16 + sr) * 64 + gls * 8,     &Qs[(wave * 16) * 64]);
  gl_lds16(Q16 + qoff + (size_t)(wave * 16 + 8 + sr) * 64 + gls * 8, &Qs[(wave * 16 + 8) * 64]);

  const size_t kbase = (size_t)bh * 1024 * 64;
  const size_t vbase = (size_t)bh * 64 * 1024;
  const f16* kp0 = K16 + kbase + (size_t)(half * 512 + wave * 16 + sr) * 64 + gls * 8;
  const f16* kp1 = kp0 + 8 * 64;
  const f16* vp0 = Vt16 + vbase + (size_t)(wave * 16 + sr) * 1024 + half * 512 + gls * 8;
  const f16* vp1 = vp0 + 8 * 1024;
  f16* lk0 = &Ks[(wave * 16) * 64];
  f16* lk1 = &Ks[(wave * 16 + 8) * 64];
  f16* lv0 = &Vs[(wave * 16) * 64];
  f16* lv1 = &Vs[(wave * 16 + 8) * 64];

  f32x4 oacc[4] = {};

  for (int ck = 0; ck < 8; ++ck) {
    __syncthreads();   // B1
    gl_lds16(kp0, lk0); gl_lds16(kp1, lk1);
    gl_lds16(vp0, lv0); gl_lds16(vp1, lv1);
    kp0 += 4096; kp1 += 4096; vp0 += 64; vp1 += 64;
    __syncthreads();   // B2

    // ---- S = Q_strip x K^T ----
    f32x4 sacc[4] = {};
    #pragma unroll
    for (int ks = 0; ks < 2; ++ks) {
      int row = wave * 16 + l15;
      int g2 = (ks * 4 + quad) ^ (row & 7);
      f16x8 aq = *(const f16x8*)&Qs[row * 64 + g2 * 8];
      #pragma unroll
      for (int j = 0; j < 4; ++j) {
        int rn = j * 16 + l15;
        int gn = (ks * 4 + quad) ^ (rn & 7);
        f16x8 bk = *(const f16x8*)&Ks[rn * 64 + gn * 8];
        sacc[j] = __builtin_amdgcn_mfma_f32_16x16x32_f16(aq, bk, sacc[j], 0, 0, 0);
      }
    }

    // ---- clamp + bias keys ----
    float svc[4][4];
    unsigned key[4][4];
    #pragma unroll
    for (int j = 0; j < 4; ++j)
      #pragma unroll
      for (int r = 0; r < 4; ++r) {
        float xx = __builtin_amdgcn_fmed3f(sacc[j][r] * rs[r], -60.0f, 60.0f);
        svc[j][r] = xx;
        key[j][r] = __builtin_bit_cast(unsigned, xx + 3072.0f);
      }

    // ---- top-32 threshold: 16-step bisection on mantissa bits 22..7 ----
    unsigned tk0 = 0x45000000u, tk1 = 0x45000000u, tk2 = 0x45000000u, tk3 = 0x45000000u;
    #pragma unroll
    for (int bit = 15; bit >= 0; --bit) {
      const unsigned bpv = 1u << (7 + bit);
      unsigned c0 = tk0 | bpv, c1 = tk1 | bpv, c2 = tk2 | bpv, c3 = tk3 | bpv;
      unsigned pk = 0;
      #pragma unroll
      for (int j = 0; j < 4; ++j) {
        pk += (key[j][0] >= c0) ? 1u : 0u;
        pk += (key[j][1] >= c1) ? 0x100u : 0u;
        pk += (key[j][2] >= c2) ? 0x10000u : 0u;
        pk += (key[j][3] >= c3) ? 0x1000000u : 0u;
      }
      pk = dpp16sum_u(pk);
      unsigned ge = ((pk | 0x80808080u) - 0x20202020u) & 0x80808080u;
      tk0 = (ge & 0x80u) ? c0 : tk0;
      tk1 = (ge & 0x8000u) ? c1 : tk1;
      tk2 = (ge & 0x800000u) ? c2 : tk2;
      tk3 = (ge & 0x80000000u) ? c3 : tk3;
    }
    const unsigned tkr0 = tk0, tkr1 = tk1, tkr2 = tk2, tkr3 = tk3;

    // ---- masked softmax (masked -> exp2(0)=1, exact) ----
    float e[4][4], dinv[4];
    {
      const unsigned tks[4] = { tkr0, tkr1, tkr2, tkr3 };
      #pragma unroll
      for (int r = 0; r < 4; ++r) {
        #pragma unroll
        for (int j = 0; j < 4; ++j) {
          float xv = (key[j][r] >= tks[r]) ? svc[j][r] : 0.0f;
          e[j][r] = EXP2(xv);
        }
        float d = (e[0][r] + e[1][r]) + (e[2][r] + e[3][r]);
        d = g16sum_f(d);
        dinv[r] = __builtin_amdgcn_rcpf(d);
      }
    }

    // ---- P -> f16 into A-operand layout (per-wave-private; no barrier) ----
    #pragma unroll
    for (int j = 0; j < 4; ++j)
      #pragma unroll
      for (int r = 0; r < 4; ++r) {
        int m = wave * 16 + quad * 4 + r;
        int c = j * 16 + l15;
        int g2 = (c >> 3) ^ (m & 7);
        Ps[m * 64 + g2 * 8 + (c & 7)] = (f16)(e[j][r] * dinv[r]);
      }

    // ---- O += P x V ----
    #pragma unroll
    for (int ks = 0; ks < 2; ++ks) {
      int row = wave * 16 + l15;
      int g2 = (ks * 4 + quad) ^ (row & 7);
      f16x8 ap2 = *(const f16x8*)&Ps[row * 64 + g2 * 8];
      #pragma unroll
      for (int j = 0; j < 4; ++j) {
        int rn = j * 16 + l15;
        int gn = (ks * 4 + quad) ^ (rn & 7);
        f16x8 bv = *(const f16x8*)&Vs[rn * 64 + gn * 8];
        oacc[j] = __builtin_amdgcn_mfma_f32_16x16x32_f16(ap2, bv, oacc[j], 0, 0, 0);
      }
    }
  }

  // raw partial (no /16 here; combine kernel applies it)
  f16* pd = half ? part1 : part0;
  #pragma unroll
  for (int j = 0; j < 4; ++j)
    #pragma unroll
    for (int r = 0; r < 4; ++r) {
      int m = wave * 16 + quad * 4 + r;
      int t = qt * 64 + m;
      int d = j * 16 + l15;
      pd[(size_t)(b * 1024 + t) * 1024 + h * 64 + d] = (f16)oacc[j][r];
    }
}

// ---------------- combine halves: O16 = (part0 + part1)/16, in-place in part1 ----
__global__ void k_combine(const f16* __restrict__ p0, f16* __restrict__ o) {
  int i = (blockIdx.x * 256 + threadIdx.x) * 8;
  f16x8 a = *(const f16x8*)(p0 + i);
  f16x8 bb = *(const f16x8*)(o + i);
  f16x8 r;
  #pragma unroll
  for (int k = 0; k < 8; ++k)
    r[k] = (f16)(((float)a[k] + (float)bb[k]) * 0.0625f);
  *(f16x8*)(o + i) = r;
}

extern "C" void kernel_launch(void* const* d_in, const int* in_sizes, int n_in,
                              void* d_out, int out_size, void* d_ws, size_t ws_size,
                              hipStream_t stream) {
  (void)in_sizes; (void)n_in; (void)out_size; (void)ws_size;
  const float* x     = (const float*)d_in[0];
  const float* imp   = (const float*)d_in[1];
  const float* temps = (const float*)d_in[2];
  const float* Wq    = (const float*)d_in[3];
  const float* Wk    = (const float*)d_in[4];
  const float* Wv    = (const float*)d_in[5];
  const float* Wo    = (const float*)d_in[6];
  float* out = (float*)d_out;

  char* w = (char*)d_ws;   // 48 MB
  f16* xh   = (f16*)w; w += (size_t)4096 * 1024 * 2;   // reused as attn part0
  f16* Wqt  = (f16*)w; w += (size_t)1024 * 1024 * 2;
  f16* Wkt  = (f16*)w; w += (size_t)1024 * 1024 * 2;
  f16* Wvt  = (f16*)w; w += (size_t)1024 * 1024 * 2;
  f16* Wot  = (f16*)w; w += (size_t)1024 * 1024 * 2;
  f16* Q16  = (f16*)w; w += (size_t)4096 * 1024 * 2;
  f16* K16  = (f16*)w; w += (size_t)4096 * 1024 * 2;
  f16* Vt16 = (f16*)w; w += (size_t)4096 * 1024 * 2;
  f16* O16  = (f16*)w; w += (size_t)4096 * 1024 * 2;   // attn part1, combined in-place

  k_prep<<<dim3(16, 16, 5), dim3(256), 0, stream>>>(x, Wq, Wk, Wv, Wo, xh, Wqt, Wkt, Wvt, Wot);
  k_gemm<0, 128><<<dim3(24, 32), dim3(256), 0, stream>>>(xh, Wqt, Wkt, Wvt,
                                                         (void*)Q16, (void*)K16, (void*)Vt16);
  k_attn<<<dim3(2048), dim3(256), 0, stream>>>(Q16, K16, Vt16, imp, temps, xh, O16);
  k_combine<<<dim3(2048), dim3(256), 0, stream>>>(xh, O16);
  k_gemm<2, 64><<<dim3(8, 64), dim3(256), 0, stream>>>(O16, Wot, nullptr, nullptr,
                                                       (void*)out, nullptr, nullptr);
}

// Round 5
// 261.952 us; speedup vs baseline: 1.6075x; 1.0300x over previous
//
#include <hip/hip_runtime.h>
#include <stdint.h>

typedef _Float16 f16;
typedef _Float16 f16x8 __attribute__((ext_vector_type(8)));
typedef _Float16 f16x4 __attribute__((ext_vector_type(4)));
typedef float f32x4 __attribute__((ext_vector_type(4)));

#define AS1 __attribute__((address_space(1)))
#define AS3 __attribute__((address_space(3)))

#if __has_builtin(__builtin_amdgcn_exp2f)
#define EXP2(x) __builtin_amdgcn_exp2f(x)
#else
#define EXP2(x) exp2f(x)
#endif

__device__ __forceinline__ void gl_lds16(const void* g, void* l) {
  __builtin_amdgcn_global_load_lds((const AS1 uint32_t*)g, (AS3 uint32_t*)l, 16, 0, 0);
}

__device__ __forceinline__ unsigned dpp16sum_u(unsigned v) {
  v += (unsigned)__builtin_amdgcn_update_dpp(0, (int)v, 0x121, 0xf, 0xf, true);
  v += (unsigned)__builtin_amdgcn_update_dpp(0, (int)v, 0x122, 0xf, 0xf, true);
  v += (unsigned)__builtin_amdgcn_update_dpp(0, (int)v, 0x124, 0xf, 0xf, true);
  v += (unsigned)__builtin_amdgcn_update_dpp(0, (int)v, 0x128, 0xf, 0xf, true);
  return v;
}
__device__ __forceinline__ float g16sum_f(float v) {
  v += __builtin_bit_cast(float, __builtin_amdgcn_update_dpp(0, __builtin_bit_cast(int, v), 0x121, 0xf, 0xf, true));
  v += __builtin_bit_cast(float, __builtin_amdgcn_update_dpp(0, __builtin_bit_cast(int, v), 0x122, 0xf, 0xf, true));
  v += __builtin_bit_cast(float, __builtin_amdgcn_update_dpp(0, __builtin_bit_cast(int, v), 0x124, 0xf, 0xf, true));
  v += __builtin_bit_cast(float, __builtin_amdgcn_update_dpp(0, __builtin_bit_cast(int, v), 0x128, 0xf, 0xf, true));
  return v;
}

// ---------- fused prep: z=0..3 -> W transpose+cvt (Wo scaled 1/16); z=4 -> x cvt ----------
__global__ void k_prep(const float* __restrict__ x,
                       const float* __restrict__ Wq, const float* __restrict__ Wk,
                       const float* __restrict__ Wv, const float* __restrict__ Wo,
                       f16* __restrict__ xh,
                       f16* __restrict__ Wqt, f16* __restrict__ Wkt,
                       f16* __restrict__ Wvt, f16* __restrict__ Wot) {
  __shared__ __align__(16) f16 lt[64][72];
  const int t = threadIdx.x;
  if (blockIdx.z == 4) {
    int bid2 = blockIdx.y * 16 + blockIdx.x;
    #pragma unroll 4
    for (int it = 0; it < 16; ++it) {
      int i = ((bid2 * 16 + it) * 256 + t) * 4;
      float4 v = *(const float4*)(x + i);
      f16x4 o = { (f16)v.x, (f16)v.y, (f16)v.z, (f16)v.w };
      *(f16x4*)(xh + i) = o;
    }
    return;
  }
  const float* src; f16* dst; float scl;
  switch (blockIdx.z) {
    case 0: src = Wq; dst = Wqt; scl = 1.0f; break;
    case 1: src = Wk; dst = Wkt; scl = 1.0f; break;
    case 2: src = Wv; dst = Wvt; scl = 1.0f; break;
    default: src = Wo; dst = Wot; scl = 0.0625f; break;   // fold attn 1/16 into Wo
  }
  int n0 = blockIdx.x * 64, k0 = blockIdx.y * 64;
  int kk = t >> 4;
  int nn = (t & 15) * 4;
  #pragma unroll
  for (int p = 0; p < 4; ++p) {
    int k = kk + p * 16;
    float4 v = *(const float4*)(src + (size_t)(k0 + k) * 1024 + n0 + nn);
    lt[nn + 0][k] = (f16)(v.x * scl);
    lt[nn + 1][k] = (f16)(v.y * scl);
    lt[nn + 2][k] = (f16)(v.z * scl);
    lt[nn + 3][k] = (f16)(v.w * scl);
  }
  __syncthreads();
  int row = t >> 2;
  int kp = (t & 3) * 16;
  f16* d = dst + (size_t)(n0 + row) * 1024 + k0 + kp;
  *(f16x8*)d       = *(const f16x8*)&lt[row][kp];
  *(f16x8*)(d + 8) = *(const f16x8*)&lt[row][kp + 8];
}

// ---------------- GEMM: C(TMxN128 per block) = A * Bt^T ----------------
// MODE 0, TM=128: A=xh; Bt0/1/2=Wqt/Wkt/Wvt; N=3072; grid(24,32).
// MODE 2, TM=64:  A=p0, A2=p1 (attention halves; staged as p0+p1); Bt0=Wot/16;
//                 out0 = f32 row-major. grid(8,64).
template<int MODE, int TM>
__global__ __launch_bounds__(256, 2)
void k_gemm(const f16* __restrict__ A, const f16* __restrict__ Bt0,
            const f16* __restrict__ A2, const f16* __restrict__ Bt2,
            const f16* __restrict__ Bt1,
            void* __restrict__ out0, void* __restrict__ out1, void* __restrict__ out2) {
  __shared__ __align__(16) f16 As[TM * 64];
  __shared__ __align__(16) f16 Bs[128 * 64];
  __shared__ __align__(16) f16 EP[(MODE == 0) ? 4 * 64 * 72 : 4];
  const int n0 = blockIdx.x * 128, m0 = blockIdx.y * TM;
  const int tid = threadIdx.x, wave = tid >> 6, lane = tid & 63;
  const int l15 = lane & 15, quad = lane >> 4;
  const int wm = (wave >> 1) * (TM / 2), wn = (wave & 1) * 64;
  constexpr int NI = TM / 32;
  constexpr int PA = TM / 32;
  const f16* Bsrc = Bt0;
  int nb = n0;
  if (MODE == 0) {
    if (n0 >= 2048)      { Bsrc = Bt2; nb = n0 - 2048; }
    else if (n0 >= 1024) { Bsrc = Bt1; nb = n0 - 1024; }
  }
  f32x4 acc[NI][4] = {};
  const int sr = lane >> 3, sg = lane & 7;
  const int gl = sg ^ sr;
  const f16* ap[PA];
  const f16* ap2[PA];
  const f16* bp[4];
  #pragma unroll
  for (int p = 0; p < PA; ++p) {
    size_t off = (size_t)(m0 + wave * (TM / 4) + p * 8 + sr) * 1024 + gl * 8;
    ap[p] = A + off;
    if (MODE == 2) ap2[p] = A2 + off;
  }
  #pragma unroll
  for (int p = 0; p < 4; ++p)
    bp[p] = Bsrc + (size_t)(nb + wave * 32 + p * 8 + sr) * 1024 + gl * 8;

  for (int kt = 0; kt < 16; ++kt) {
    __syncthreads();
    #pragma unroll
    for (int p = 0; p < PA; ++p) {
      if (MODE == 2) {
        // stage A = p0 + p1 (combine attention halves in-flight)
        f16x8 a0 = *(const f16x8*)ap[p];
        f16x8 a1 = *(const f16x8*)ap2[p];
        *(f16x8*)&As[(wave * (TM / 4) + p * 8) * 64 + lane * 8] = a0 + a1;
        ap2[p] += 64;
      } else {
        gl_lds16(ap[p], &As[(wave * (TM / 4) + p * 8) * 64]);
      }
      ap[p] += 64;
    }
    #pragma unroll
    for (int p = 0; p < 4; ++p) {
      gl_lds16(bp[p], &Bs[(wave * 32 + p * 8) * 64]);
      bp[p] += 64;
    }
    __syncthreads();
    #pragma unroll
    for (int ks = 0; ks < 2; ++ks) {
      f16x8 af[NI], bf[4];
      #pragma unroll
      for (int i = 0; i < NI; ++i) {
        int row = wm + i * 16 + l15;
        int g2 = (ks * 4 + quad) ^ (row & 7);
        af[i] = *(const f16x8*)&As[row * 64 + g2 * 8];
      }
      #pragma unroll
      for (int j = 0; j < 4; ++j) {
        int row = wn + j * 16 + l15;
        int g2 = (ks * 4 + quad) ^ (row & 7);
        bf[j] = *(const f16x8*)&Bs[row * 64 + g2 * 8];
      }
      #pragma unroll
      for (int i = 0; i < NI; ++i)
        #pragma unroll
        for (int j = 0; j < 4; ++j)
          acc[i][j] = __builtin_amdgcn_mfma_f32_16x16x32_f16(af[i], bf[j], acc[i][j], 0, 0, 0);
    }
  }

  if (MODE == 0) {
    if (n0 < 2048) {
      f16* ep = &EP[wave * 64 * 72];
      #pragma unroll
      for (int i = 0; i < NI; ++i)
        #pragma unroll
        for (int j = 0; j < 4; ++j)
          #pragma unroll
          for (int r = 0; r < 4; ++r)
            ep[(i * 16 + quad * 4 + r) * 72 + j * 16 + l15] = (f16)acc[i][j][r];
      f16* dst = (n0 < 1024) ? (f16*)out0 : (f16*)out1;
      const int hh = ((n0 + wn) & 1023) >> 6;
      const int r8 = lane >> 3, cg = lane & 7;
      #pragma unroll
      for (int it = 0; it < 8; ++it) {
        int row = it * 8 + r8;
        f16x8 vv = *(const f16x8*)&ep[row * 72 + cg * 8];
        int m = m0 + wm + row;
        int b = m >> 10, t = m & 1023;
        *(f16x8*)&dst[(size_t)((b * 16 + hh) * 1024 + t) * 64 + cg * 8] = vv;
      }
    } else {
      #pragma unroll
      for (int i = 0; i < NI; ++i)
        #pragma unroll
        for (int j = 0; j < 4; ++j) {
          int mb = m0 + wm + i * 16 + quad * 4;
          int b = mb >> 10, t = mb & 1023;
          int n = n0 + wn + j * 16 + l15;
          int nn2 = n & 1023, hh = nn2 >> 6, d = nn2 & 63;
          f16x4 vv = { (f16)acc[i][j][0], (f16)acc[i][j][1], (f16)acc[i][j][2], (f16)acc[i][j][3] };
          *(f16x4*)((f16*)out2 + ((size_t)(b * 16 + hh) * 64 + d) * 1024 + t) = vv;
        }
    }
  } else {
    #pragma unroll
    for (int i = 0; i < NI; ++i)
      #pragma unroll
      for (int j = 0; j < 4; ++j)
        #pragma unroll
        for (int r = 0; r < 4; ++r) {
          int m = m0 + wm + i * 16 + quad * 4 + r;
          int n = n0 + wn + j * 16 + l15;
          ((float*)out0)[(size_t)m * 1024 + n] = acc[i][j][r];
        }
  }
}

// ---------------- fused sparse attention (half the chunks per block) ----------------
// grid 2048. Bias-192 keys: svc = med3(s',-60,60); key = bits(svc+192) — all keys
// in octave [128,256) (exp 0x43), uint-monotone; bisect mantissa bits 22..10
// (13 steps, granularity 2^-6). Counts byte-packed, 4 DPP per step.
__global__ __launch_bounds__(256, 4)
void k_attn(const f16* __restrict__ Q16, const f16* __restrict__ K16, const f16* __restrict__ Vt16,
            const float* __restrict__ imp, const float* __restrict__ temps,
            f16* __restrict__ part0, f16* __restrict__ part1) {
  __shared__ __align__(16) f16 Qs[64 * 64];
  __shared__ __align__(16) f16 Ks[64 * 64];
  __shared__ __align__(16) f16 Vs[64 * 64];
  __shared__ __align__(16) f16 Ps[64 * 64];

  const int bid = blockIdx.x & 1023;
  const int half = blockIdx.x >> 10;
  const int b = bid >> 8, h = (bid >> 4) & 15, qt = bid & 15;
  const int bh = b * 16 + h;
  const int tid = threadIdx.x, wave = tid >> 6, lane = tid & 63;
  const int l15 = lane & 15, quad = lane >> 4;

  float sc = (0.125f * 1.44269504088896340736f) / fminf(fmaxf(temps[bh], 0.1f), 100.0f);
  float rs[4];
  #pragma unroll
  for (int r = 0; r < 4; ++r) {
    int m = wave * 16 + quad * 4 + r;
    int t = qt * 64 + m;
    float is = imp[(size_t)(b * 1024 + t) * 16 + h];
    float s1 = 1.0f / (1.0f + __expf(-is));
    float mwv = 1.0f / (1.0f + __expf(-(s1 - 0.5f) * 10.0f));
    rs[r] = sc * mwv;
  }

  const int sr = lane >> 3, sg = lane & 7;
  const int gls = sg ^ sr;
  const size_t qoff = ((size_t)bh * 1024 + qt * 64) * 64;
  gl_lds16(Q16 + qoff + (size_t)(wave * 16 + sr) * 64 + gls * 8,     &Qs[(wave * 16) * 64]);
  gl_lds16(Q16 + qoff + (size_t)(wave * 16 + 8 + sr) * 64 + gls * 8, &Qs[(wave * 16 + 8) * 64]);

  const size_t kbase = (size_t)bh * 1024 * 64;
  const size_t vbase = (size_t)bh * 64 * 1024;
  const f16* kp0 = K16 + kbase + (size_t)(half * 512 + wave * 16 + sr) * 64 + gls * 8;
  const f16* kp1 = kp0 + 8 * 64;
  const f16* vp0 = Vt16 + vbase + (size_t)(wave * 16 + sr) * 1024 + half * 512 + gls * 8;
  const f16* vp1 = vp0 + 8 * 1024;
  f16* lk0 = &Ks[(wave * 16) * 64];
  f16* lk1 = &Ks[(wave * 16 + 8) * 64];
  f16* lv0 = &Vs[(wave * 16) * 64];
  f16* lv1 = &Vs[(wave * 16 + 8) * 64];

  f32x4 oacc[4] = {};

  for (int ck = 0; ck < 8; ++ck) {
    __syncthreads();   // B1
    gl_lds16(kp0, lk0); gl_lds16(kp1, lk1);
    gl_lds16(vp0, lv0); gl_lds16(vp1, lv1);
    kp0 += 4096; kp1 += 4096; vp0 += 64; vp1 += 64;
    __syncthreads();   // B2

    // ---- S = Q_strip x K^T ----
    f32x4 sacc[4] = {};
    #pragma unroll
    for (int ks = 0; ks < 2; ++ks) {
      int row = wave * 16 + l15;
      int g2 = (ks * 4 + quad) ^ (row & 7);
      f16x8 aq = *(const f16x8*)&Qs[row * 64 + g2 * 8];
      #pragma unroll
      for (int j = 0; j < 4; ++j) {
        int rn = j * 16 + l15;
        int gn = (ks * 4 + quad) ^ (rn & 7);
        f16x8 bk = *(const f16x8*)&Ks[rn * 64 + gn * 8];
        sacc[j] = __builtin_amdgcn_mfma_f32_16x16x32_f16(aq, bk, sacc[j], 0, 0, 0);
      }
    }

    // ---- clamp + bias-192 keys ----
    float svc[4][4];
    unsigned key[4][4];
    #pragma unroll
    for (int j = 0; j < 4; ++j)
      #pragma unroll
      for (int r = 0; r < 4; ++r) {
        float xx = __builtin_amdgcn_fmed3f(sacc[j][r] * rs[r], -60.0f, 60.0f);
        svc[j][r] = xx;
        key[j][r] = __builtin_bit_cast(unsigned, xx + 192.0f);
      }

    // ---- top-32 threshold: 13-step bisection on mantissa bits 22..10 ----
    unsigned tk0 = 0x43000000u, tk1 = 0x43000000u, tk2 = 0x43000000u, tk3 = 0x43000000u;
    #pragma unroll
    for (int bit = 12; bit >= 0; --bit) {
      const unsigned bpv = 1u << (10 + bit);
      unsigned c0 = tk0 | bpv, c1 = tk1 | bpv, c2 = tk2 | bpv, c3 = tk3 | bpv;
      unsigned pk = 0;
      #pragma unroll
      for (int j = 0; j < 4; ++j) {
        pk += (key[j][0] >= c0) ? 1u : 0u;
        pk += (key[j][1] >= c1) ? 0x100u : 0u;
        pk += (key[j][2] >= c2) ? 0x10000u : 0u;
        pk += (key[j][3] >= c3) ? 0x1000000u : 0u;
      }
      pk = dpp16sum_u(pk);
      unsigned ge = ((pk | 0x80808080u) - 0x20202020u) & 0x80808080u;
      tk0 = (ge & 0x80u) ? c0 : tk0;
      tk1 = (ge & 0x8000u) ? c1 : tk1;
      tk2 = (ge & 0x800000u) ? c2 : tk2;
      tk3 = (ge & 0x80000000u) ? c3 : tk3;
    }

    // ---- masked softmax (masked -> exp2(0)=1, exact) ----
    float e[4][4], dinv[4];
    #pragma unroll
    for (int r = 0; r < 4; ++r) {
      const unsigned tkc = (r == 0) ? tk0 : (r == 1) ? tk1 : (r == 2) ? tk2 : tk3;
      #pragma unroll
      for (int j = 0; j < 4; ++j) {
        float xv = (key[j][r] >= tkc) ? svc[j][r] : 0.0f;
        e[j][r] = EXP2(xv);
      }
      float d = (e[0][r] + e[1][r]) + (e[2][r] + e[3][r]);
      d = g16sum_f(d);
      dinv[r] = __builtin_amdgcn_rcpf(d);
    }

    // ---- P -> f16 into A-operand layout (per-wave-private; no barrier) ----
    #pragma unroll
    for (int j = 0; j < 4; ++j)
      #pragma unroll
      for (int r = 0; r < 4; ++r) {
        int m = wave * 16 + quad * 4 + r;
        int c = j * 16 + l15;
        int g2 = (c >> 3) ^ (m & 7);
        Ps[m * 64 + g2 * 8 + (c & 7)] = (f16)(e[j][r] * dinv[r]);
      }

    // ---- O += P x V ----
    #pragma unroll
    for (int ks = 0; ks < 2; ++ks) {
      int row = wave * 16 + l15;
      int g2 = (ks * 4 + quad) ^ (row & 7);
      f16x8 ap2 = *(const f16x8*)&Ps[row * 64 + g2 * 8];
      #pragma unroll
      for (int j = 0; j < 4; ++j) {
        int rn = j * 16 + l15;
        int gn = (ks * 4 + quad) ^ (rn & 7);
        f16x8 bv = *(const f16x8*)&Vs[rn * 64 + gn * 8];
        oacc[j] = __builtin_amdgcn_mfma_f32_16x16x32_f16(ap2, bv, oacc[j], 0, 0, 0);
      }
    }
  }

  // raw partial; 1/16 is folded into Wot, halves combined in k_gemm<2> staging
  f16* pd = half ? part1 : part0;
  #pragma unroll
  for (int j = 0; j < 4; ++j)
    #pragma unroll
    for (int r = 0; r < 4; ++r) {
      int m = wave * 16 + quad * 4 + r;
      int t = qt * 64 + m;
      int d = j * 16 + l15;
      pd[(size_t)(b * 1024 + t) * 1024 + h * 64 + d] = (f16)oacc[j][r];
    }
}

extern "C" void kernel_launch(void* const* d_in, const int* in_sizes, int n_in,
                              void* d_out, int out_size, void* d_ws, size_t ws_size,
                              hipStream_t stream) {
  (void)in_sizes; (void)n_in; (void)out_size; (void)ws_size;
  const float* x     = (const float*)d_in[0];
  const float* imp   = (const float*)d_in[1];
  const float* temps = (const float*)d_in[2];
  const float* Wq    = (const float*)d_in[3];
  const float* Wk    = (const float*)d_in[4];
  const float* Wv    = (const float*)d_in[5];
  const float* Wo    = (const float*)d_in[6];
  float* out = (float*)d_out;

  char* w = (char*)d_ws;   // 48 MB
  f16* xh   = (f16*)w; w += (size_t)4096 * 1024 * 2;   // reused as attn part0
  f16* Wqt  = (f16*)w; w += (size_t)1024 * 1024 * 2;
  f16* Wkt  = (f16*)w; w += (size_t)1024 * 1024 * 2;
  f16* Wvt  = (f16*)w; w += (size_t)1024 * 1024 * 2;
  f16* Wot  = (f16*)w; w += (size_t)1024 * 1024 * 2;   // pre-scaled by 1/16
  f16* Q16  = (f16*)w; w += (size_t)4096 * 1024 * 2;
  f16* K16  = (f16*)w; w += (size_t)4096 * 1024 * 2;
  f16* Vt16 = (f16*)w; w += (size_t)4096 * 1024 * 2;
  f16* O16  = (f16*)w; w += (size_t)4096 * 1024 * 2;   // attn part1

  k_prep<<<dim3(16, 16, 5), dim3(256), 0, stream>>>(x, Wq, Wk, Wv, Wo, xh, Wqt, Wkt, Wvt, Wot);
  k_gemm<0, 128><<<dim3(24, 32), dim3(256), 0, stream>>>(xh, Wqt, nullptr, Wvt, Wkt,
                                                         (void*)Q16, (void*)K16, (void*)Vt16);
  k_attn<<<dim3(2048), dim3(256), 0, stream>>>(Q16, K16, Vt16, imp, temps, xh, O16);
  k_gemm<2, 64><<<dim3(8, 64), dim3(256), 0, stream>>>(xh, Wot, O16, nullptr, nullptr,
                                                       (void*)out, nullptr, nullptr);
}